// Round 1
// baseline (1173.386 us; speedup 1.0000x reference)
//
#include <hip/hip_runtime.h>
#include <hip/hip_bf16.h>
#include <cmath>

#define AS_GLOBAL __attribute__((address_space(1)))
#define AS_LDS    __attribute__((address_space(3)))

typedef __attribute__((ext_vector_type(8))) short bf16x8;
typedef __attribute__((ext_vector_type(4))) float f32x4;
typedef unsigned short u16;

__device__ __forceinline__ u16 f2bf(float f) {
  union { __hip_bfloat16 h; u16 u; } cv;
  cv.h = __float2bfloat16(f);
  return cv.u;
}
__device__ __forceinline__ float bf2f(u16 u) {
  union { unsigned u32; float f; } v;
  v.u32 = ((unsigned)u) << 16;
  return v.f;
}

// ---------------------------------------------------------------- prep kernels

__global__ void k_f32_to_bf16(const float* __restrict__ in, u16* __restrict__ out, int n4) {
  int i = blockIdx.x * 256 + threadIdx.x;
  if (i >= n4) return;
  float4 v = ((const float4*)in)[i];
  ushort4 o;
  o.x = f2bf(v.x); o.y = f2bf(v.y); o.z = f2bf(v.z); o.w = f2bf(v.w);
  ((ushort4*)out)[i] = o;
}

// out[n][k] = bf16(in[k][n]), 1024x1024
__global__ void k_transpose_w(const float* __restrict__ in, u16* __restrict__ out) {
  __shared__ float tile[32][33];
  const int tx = threadIdx.x & 31;
  const int ty = threadIdx.x >> 5;  // 0..7
  const int x0 = blockIdx.x * 32, y0 = blockIdx.y * 32;
  #pragma unroll
  for (int i = 0; i < 32; i += 8)
    tile[ty + i][tx] = in[(size_t)(y0 + ty + i) * 1024 + x0 + tx];
  __syncthreads();
  #pragma unroll
  for (int i = 0; i < 32; i += 8)
    out[(size_t)(x0 + ty + i) * 1024 + y0 + tx] = f2bf(tile[tx][ty + i]);
}

// qscale[n] = Q_SCALE * softplus(pds[n % 128]), n in [0,1024)
__global__ void k_qscale(const float* __restrict__ pds, float* __restrict__ qs, float qscale_c) {
  int n = blockIdx.x * 256 + threadIdx.x;
  float s = pds[n & 127];
  qs[n] = qscale_c * log1pf(expf(s));
}

// relk[p][n] = sum_k pos[p][k] * Wrel[k][n]  (Wrel given transposed bf16: wrt[n][k])
__global__ void k_relk(const float* __restrict__ pos, const u16* __restrict__ wrt,
                       float* __restrict__ relk) {
  __shared__ float prow[1024];
  const int tid = threadIdx.x;
  const int p = blockIdx.y;
  ((float4*)prow)[tid] = ((const float4*)(pos + (size_t)p * 1024))[tid];
  __syncthreads();
  int nn = blockIdx.x * 256 + tid;
  const u16* wr = wrt + (size_t)nn * 1024;
  float acc = 0.f;
  for (int kk = 0; kk < 1024; kk += 8) {
    ushort4 u0 = *(const ushort4*)(wr + kk);
    ushort4 u1 = *(const ushort4*)(wr + kk + 4);
    acc += bf2f(u0.x) * prow[kk + 0] + bf2f(u0.y) * prow[kk + 1]
         + bf2f(u0.z) * prow[kk + 2] + bf2f(u0.w) * prow[kk + 3]
         + bf2f(u1.x) * prow[kk + 4] + bf2f(u1.y) * prow[kk + 5]
         + bf2f(u1.z) * prow[kk + 6] + bf2f(u1.w) * prow[kk + 7];
  }
  relk[(size_t)p * 1024 + nn] = acc;
}

// ---------------------------------------------------------------- GEMM (m97 structure)
// C[M,N] = A[M,K] @ Bt[N,K]^T ; A,Bt bf16 row-major; 128x128 tile, BK=32,
// 4 waves in 2x2, each wave 64x64 via 4x4 of mfma_f32_16x16x32_bf16.
// OUTBF: 1 -> bf16 out, 0 -> fp32 out. Per-column scale via scale_vec (nullable) or scalar.
template <int OUTBF>
__global__ __launch_bounds__(256) void k_gemm_bt(
    const u16* __restrict__ A, const u16* __restrict__ Bt, void* __restrict__ Cout,
    const float* __restrict__ scale_vec, float scale_scalar, int M, int N, int K) {
  __shared__ __align__(16) u16 As[128 * 32];
  __shared__ __align__(16) u16 Bs[128 * 32];
  const int tid = threadIdx.x;
  const int wave = tid >> 6, lane = tid & 63;
  const int quad = lane >> 4, l16 = lane & 15;
  const int wm = wave >> 1, wn = wave & 1;
  const int m0 = blockIdx.y * 128, n0 = blockIdx.x * 128;

  f32x4 acc[4][4];
  #pragma unroll
  for (int i = 0; i < 4; ++i)
    #pragma unroll
    for (int j = 0; j < 4; ++j) {
      f32x4 z = {0.f, 0.f, 0.f, 0.f};
      acc[i][j] = z;
    }

  for (int k0 = 0; k0 < K; k0 += 32) {
    __syncthreads();  // prior compute done before overwriting LDS
    // stage A-tile and Bt-tile: 512 chunks of 16B each (row = c>>2, colgrp = c&3)
    #pragma unroll
    for (int i = 0; i < 2; ++i) {
      int cbase = i * 256 + wave * 64;  // wave-uniform
      int c = cbase + lane;
      const u16* ga = A + (size_t)(m0 + (c >> 2)) * K + (k0 + (c & 3) * 8);
      __builtin_amdgcn_global_load_lds((const AS_GLOBAL u16*)ga, (AS_LDS u16*)&As[cbase * 8], 16, 0, 0);
      const u16* gb = Bt + (size_t)(n0 + (c >> 2)) * K + (k0 + (c & 3) * 8);
      __builtin_amdgcn_global_load_lds((const AS_GLOBAL u16*)gb, (AS_LDS u16*)&Bs[cbase * 8], 16, 0, 0);
    }
    __syncthreads();  // drains vmcnt -> staged data visible

    bf16x8 af[4], bfr[4];
    #pragma unroll
    for (int mi = 0; mi < 4; ++mi)
      af[mi] = *(const bf16x8*)&As[(wm * 64 + mi * 16 + l16) * 32 + quad * 8];
    #pragma unroll
    for (int ni = 0; ni < 4; ++ni)
      bfr[ni] = *(const bf16x8*)&Bs[(wn * 64 + ni * 16 + l16) * 32 + quad * 8];
    #pragma unroll
    for (int mi = 0; mi < 4; ++mi)
      #pragma unroll
      for (int ni = 0; ni < 4; ++ni)
        acc[mi][ni] = __builtin_amdgcn_mfma_f32_16x16x32_bf16(af[mi], bfr[ni], acc[mi][ni], 0, 0, 0);
  }

  // epilogue: D row = quad*4 + reg, col = l16 within each 16x16 tile
  #pragma unroll
  for (int ni = 0; ni < 4; ++ni) {
    int col = n0 + wn * 64 + ni * 16 + l16;
    float cs = scale_vec ? scale_vec[col] : scale_scalar;
    #pragma unroll
    for (int mi = 0; mi < 4; ++mi) {
      int row = m0 + wm * 64 + mi * 16 + quad * 4;
      #pragma unroll
      for (int r = 0; r < 4; ++r) {
        float v = acc[mi][ni][r] * cs;
        if (OUTBF)
          ((u16*)Cout)[(size_t)(row + r) * N + col] = f2bf(v);
        else
          ((float*)Cout)[(size_t)(row + r) * N + col] = v;
      }
    }
  }
}

// ---------------------------------------------------------------- attention
// One block per (b, n, h). CHUNK=12, PAST=12, CTX=24, P=25, D=128, SOFTCAP=50.
// rel-shift collapses to: shifted[q][k] = bd_flat[q*24+k], bd_flat = row-major [12][25].
#define APITCH 132
__global__ __launch_bounds__(256) void k_attn(
    const u16* __restrict__ q, const u16* __restrict__ k, const u16* __restrict__ v,
    const float* __restrict__ relk, u16* __restrict__ ctx) {
  __shared__ __align__(16) float qs[12 * APITCH];
  __shared__ __align__(16) float ks[24 * APITCH];
  __shared__ __align__(16) float vs[24 * APITCH];
  __shared__ __align__(16) float rl[25 * APITCH];
  __shared__ float sc[288];
  __shared__ float bdm[300];

  const int tid = threadIdx.x;
  const int bx = blockIdx.x;
  const int b = bx / 1600;          // nb*H = 200*8
  const int rr = bx % 1600;
  const int n = rr >> 3;
  const int h = rr & 7;
  const int s0 = n * 12;

  // load q (12 rows), k (24 rows), v (24 rows): 60 rows x 16 chunks of 8 bf16
  for (int c = tid; c < 960; c += 256) {
    int rowi = c >> 4, cc = (c & 15) * 8;
    const u16* src;
    float* dst;
    int s;
    if (rowi < 12)      { s = s0 + rowi;           src = q; dst = &qs[rowi * APITCH + cc]; }
    else if (rowi < 36) { s = s0 + (rowi - 12) - 12; src = k; dst = &ks[(rowi - 12) * APITCH + cc]; }
    else                { s = s0 + (rowi - 36) - 12; src = v; dst = &vs[(rowi - 36) * APITCH + cc]; }
    if (s < 0 || s >= 2400) {
      #pragma unroll
      for (int j = 0; j < 8; ++j) dst[j] = 0.f;
    } else {
      const u16* p = src + ((size_t)(b * 2400 + s) * 1024 + h * 128 + cc);
      ushort4 u0 = *(const ushort4*)p;
      ushort4 u1 = *(const ushort4*)(p + 4);
      dst[0] = bf2f(u0.x); dst[1] = bf2f(u0.y); dst[2] = bf2f(u0.z); dst[3] = bf2f(u0.w);
      dst[4] = bf2f(u1.x); dst[5] = bf2f(u1.y); dst[6] = bf2f(u1.z); dst[7] = bf2f(u1.w);
    }
  }
  // load rel_k for this head: 25 rows x 32 float4 chunks
  for (int c = tid; c < 800; c += 256) {
    int pi = c >> 5, cc = (c & 31) * 4;
    float4 vv = *(const float4*)&relk[(size_t)pi * 1024 + h * 128 + cc];
    float* dst = &rl[pi * APITCH + cc];
    dst[0] = vv.x; dst[1] = vv.y; dst[2] = vv.z; dst[3] = vv.w;
  }
  __syncthreads();

  // content-content scores: 12x24 dots over D=128
  for (int idx = tid; idx < 288; idx += 256) {
    int qi = idx / 24, ki = idx % 24;
    const float* qp = &qs[qi * APITCH];
    const float* kp = &ks[ki * APITCH];
    float acc = 0.f;
    #pragma unroll 4
    for (int d = 0; d < 128; d += 4) {
      float4 a = *(const float4*)&qp[d];
      float4 bb = *(const float4*)&kp[d];
      acc += a.x * bb.x + a.y * bb.y + a.z * bb.z + a.w * bb.w;
    }
    sc[idx] = acc;
  }
  // content-position: 12x25 dots over D=128
  for (int idx = tid; idx < 300; idx += 256) {
    int qi = idx / 25, pi = idx % 25;
    const float* qp = &qs[qi * APITCH];
    const float* rp = &rl[pi * APITCH];
    float acc = 0.f;
    #pragma unroll 4
    for (int d = 0; d < 128; d += 4) {
      float4 a = *(const float4*)&qp[d];
      float4 bb = *(const float4*)&rp[d];
      acc += a.x * bb.x + a.y * bb.y + a.z * bb.z + a.w * bb.w;
    }
    bdm[idx] = acc;
  }
  __syncthreads();

  // combine (rel-shift = flat reindex) + softcap
  for (int idx = tid; idx < 288; idx += 256) {
    float sv = (sc[idx] + bdm[idx]) * (1.0f / 50.0f);
    sc[idx] = tanhf(sv) * 50.0f;
  }
  __syncthreads();

  // softmax over k (24), one thread per q-row
  if (tid < 12) {
    float mx = -1e30f;
    #pragma unroll
    for (int t = 0; t < 24; ++t) mx = fmaxf(mx, sc[tid * 24 + t]);
    float sum = 0.f;
    #pragma unroll
    for (int t = 0; t < 24; ++t) sum += expf(sc[tid * 24 + t] - mx);
    float inv = 1.0f / sum;
    #pragma unroll
    for (int t = 0; t < 24; ++t) sc[tid * 24 + t] = expf(sc[tid * 24 + t] - mx) * inv;
  }
  __syncthreads();

  // out[qi][d] = sum_t attn[qi][t] * v[t][d]
  for (int idx = tid; idx < 1536; idx += 256) {
    int qi = idx >> 7, d = idx & 127;
    const float* ap = &sc[qi * 24];
    float acc = 0.f;
    #pragma unroll
    for (int t = 0; t < 24; ++t) acc += ap[t] * vs[t * APITCH + d];
    ctx[(size_t)(b * 2400 + s0 + qi) * 1024 + h * 128 + d] = f2bf(acc);
  }
}

// ---------------------------------------------------------------- launch

extern "C" void kernel_launch(void* const* d_in, const int* in_sizes, int n_in,
                              void* d_out, int out_size, void* d_ws, size_t ws_size,
                              hipStream_t stream) {
  const float* x       = (const float*)d_in[0];  // [16,2400,1024]
  const float* pos_emb = (const float*)d_in[1];  // [25,1024]
  const float* Wq      = (const float*)d_in[2];
  const float* Wk      = (const float*)d_in[3];
  const float* Wv      = (const float*)d_in[4];
  const float* Wpost   = (const float*)d_in[5];
  const float* Wrel    = (const float*)d_in[6];
  const float* pds     = (const float*)d_in[7];  // [128]
  float* out = (float*)d_out;

  const int M = 38400, HS = 1024;           // M = B*S = 16*2400
  const size_t XE = (size_t)M * HS;         // 39321600

  // workspace layout (bf16 = u16)
  u16* xbf = (u16*)d_ws;        // also reused as ctx after QKV GEMMs consume it
  u16* qbf = xbf + XE;
  u16* kbf = qbf + XE;
  u16* vbf = kbf + XE;
  u16* wqt = vbf + XE;
  u16* wkt = wqt + (size_t)HS * HS;
  u16* wvt = wkt + (size_t)HS * HS;
  u16* wrt = wvt + (size_t)HS * HS;
  u16* wpt = wrt + (size_t)HS * HS;
  float* relk = (float*)(wpt + (size_t)HS * HS);
  float* qsc  = relk + 25 * 1024;

  const double LN2 = 0.6931471805599453;
  const float QS = (float)((1.0 / sqrt(128.0)) / LN2);
  const float KS = (float)(log(1.0 + exp(1.0)) / LN2);

  // 1) x -> bf16
  k_f32_to_bf16<<<(int)(XE / 4 / 256), 256, 0, stream>>>(x, xbf, (int)(XE / 4));
  // 2) transpose weights -> bf16 [n][k]
  dim3 tg(32, 32);
  k_transpose_w<<<tg, 256, 0, stream>>>(Wq, wqt);
  k_transpose_w<<<tg, 256, 0, stream>>>(Wk, wkt);
  k_transpose_w<<<tg, 256, 0, stream>>>(Wv, wvt);
  k_transpose_w<<<tg, 256, 0, stream>>>(Wrel, wrt);
  k_transpose_w<<<tg, 256, 0, stream>>>(Wpost, wpt);
  // 3) per-column q scale
  k_qscale<<<4, 256, 0, stream>>>(pds, qsc, QS);
  // 4) rel_k = pos_emb @ Wrel (fp32 out)
  k_relk<<<dim3(4, 25), 256, 0, stream>>>(pos_emb, wrt, relk);
  // 5) QKV projections (bf16 out)
  dim3 gg(HS / 128, M / 128);  // (8, 300)
  k_gemm_bt<1><<<gg, 256, 0, stream>>>(xbf, wqt, qbf, qsc, 1.0f, M, HS, HS);
  k_gemm_bt<1><<<gg, 256, 0, stream>>>(xbf, wkt, kbf, nullptr, KS, M, HS, HS);
  k_gemm_bt<1><<<gg, 256, 0, stream>>>(xbf, wvt, vbf, nullptr, 1.0f, M, HS, HS);
  // 6) attention -> ctx (reuses xbf region; safe: stream-ordered after QKV reads)
  k_attn<<<16 * 200 * 8, 256, 0, stream>>>(qbf, kbf, vbf, relk, xbf);
  // 7) out = ctx @ Wpost (fp32 out)
  k_gemm_bt<0><<<gg, 256, 0, stream>>>(xbf, wpt, out, nullptr, 1.0f, M, HS, HS);
}

// Round 2
// 963.917 us; speedup vs baseline: 1.2173x; 1.2173x over previous
//
#include <hip/hip_runtime.h>
#include <hip/hip_bf16.h>
#include <cmath>

#define AS_GLOBAL __attribute__((address_space(1)))
#define AS_LDS    __attribute__((address_space(3)))

typedef __attribute__((ext_vector_type(8))) short bf16x8;
typedef __attribute__((ext_vector_type(4))) float f32x4;
typedef unsigned short u16;

__device__ __forceinline__ u16 f2bf(float f) {
  union { __hip_bfloat16 h; u16 u; } cv;
  cv.h = __float2bfloat16(f);
  return cv.u;
}
__device__ __forceinline__ float bf2f(u16 u) {
  union { unsigned u32; float f; } v;
  v.u32 = ((unsigned)u) << 16;
  return v.f;
}

// ---------------------------------------------------------------- prep kernels

__global__ void k_f32_to_bf16(const float* __restrict__ in, u16* __restrict__ out, int n4) {
  int i = blockIdx.x * 256 + threadIdx.x;
  if (i >= n4) return;
  float4 v = ((const float4*)in)[i];
  ushort4 o;
  o.x = f2bf(v.x); o.y = f2bf(v.y); o.z = f2bf(v.z); o.w = f2bf(v.w);
  ((ushort4*)out)[i] = o;
}

// out[n][k] = bf16(in[k][n]), 1024x1024
__global__ void k_transpose_w(const float* __restrict__ in, u16* __restrict__ out) {
  __shared__ float tile[32][33];
  const int tx = threadIdx.x & 31;
  const int ty = threadIdx.x >> 5;  // 0..7
  const int x0 = blockIdx.x * 32, y0 = blockIdx.y * 32;
  #pragma unroll
  for (int i = 0; i < 32; i += 8)
    tile[ty + i][tx] = in[(size_t)(y0 + ty + i) * 1024 + x0 + tx];
  __syncthreads();
  #pragma unroll
  for (int i = 0; i < 32; i += 8)
    out[(size_t)(x0 + ty + i) * 1024 + y0 + tx] = f2bf(tile[tx][ty + i]);
}

// qscale[n] = Q_SCALE * softplus(pds[n % 128]), n in [0,1024)
__global__ void k_qscale(const float* __restrict__ pds, float* __restrict__ qs, float qscale_c) {
  int n = blockIdx.x * 256 + threadIdx.x;
  float s = pds[n & 127];
  qs[n] = qscale_c * log1pf(expf(s));
}

// relkb[p][n] = bf16( sum_k pos[p][k] * Wrel[k][n] )  (wrt = Wrel^T bf16)
__global__ void k_relk(const float* __restrict__ pos, const u16* __restrict__ wrt,
                       u16* __restrict__ relkb) {
  __shared__ float prow[1024];
  const int tid = threadIdx.x;
  const int p = blockIdx.y;
  ((float4*)prow)[tid] = ((const float4*)(pos + (size_t)p * 1024))[tid];
  __syncthreads();
  int nn = blockIdx.x * 256 + tid;
  const u16* wr = wrt + (size_t)nn * 1024;
  float acc = 0.f;
  for (int kk = 0; kk < 1024; kk += 8) {
    ushort4 u0 = *(const ushort4*)(wr + kk);
    ushort4 u1 = *(const ushort4*)(wr + kk + 4);
    acc += bf2f(u0.x) * prow[kk + 0] + bf2f(u0.y) * prow[kk + 1]
         + bf2f(u0.z) * prow[kk + 2] + bf2f(u0.w) * prow[kk + 3]
         + bf2f(u1.x) * prow[kk + 4] + bf2f(u1.y) * prow[kk + 5]
         + bf2f(u1.z) * prow[kk + 6] + bf2f(u1.w) * prow[kk + 7];
  }
  relkb[(size_t)p * 1024 + nn] = f2bf(acc);
}

// ---------------------------------------------------------------- GEMM (m97 structure)
// C[M,N] = A[M,K] @ Bt[N,K]^T ; A,Bt bf16 row-major; 128x128 tile, BK=32,
// 4 waves in 2x2, each wave 64x64 via 4x4 of mfma_f32_16x16x32_bf16.
// OUTMODE: 0 -> fp32 row-major, 1 -> bf16 row-major, 2 -> bf16 TRANSPOSED (Cout[col*M+row])
template <int OUTMODE>
__global__ __launch_bounds__(256) void k_gemm_bt(
    const u16* __restrict__ A, const u16* __restrict__ Bt, void* __restrict__ Cout,
    const float* __restrict__ scale_vec, float scale_scalar, int M, int N, int K) {
  __shared__ __align__(16) u16 As[128 * 32];
  __shared__ __align__(16) u16 Bs[128 * 32];
  const int tid = threadIdx.x;
  const int wave = tid >> 6, lane = tid & 63;
  const int quad = lane >> 4, l16 = lane & 15;
  const int wm = wave >> 1, wn = wave & 1;
  const int m0 = blockIdx.y * 128, n0 = blockIdx.x * 128;

  f32x4 acc[4][4];
  #pragma unroll
  for (int i = 0; i < 4; ++i)
    #pragma unroll
    for (int j = 0; j < 4; ++j) {
      f32x4 z = {0.f, 0.f, 0.f, 0.f};
      acc[i][j] = z;
    }

  for (int k0 = 0; k0 < K; k0 += 32) {
    __syncthreads();
    #pragma unroll
    for (int i = 0; i < 2; ++i) {
      int cbase = i * 256 + wave * 64;
      int c = cbase + lane;
      const u16* ga = A + (size_t)(m0 + (c >> 2)) * K + (k0 + (c & 3) * 8);
      __builtin_amdgcn_global_load_lds((const AS_GLOBAL u16*)ga, (AS_LDS u16*)&As[cbase * 8], 16, 0, 0);
      const u16* gb = Bt + (size_t)(n0 + (c >> 2)) * K + (k0 + (c & 3) * 8);
      __builtin_amdgcn_global_load_lds((const AS_GLOBAL u16*)gb, (AS_LDS u16*)&Bs[cbase * 8], 16, 0, 0);
    }
    __syncthreads();

    bf16x8 af[4], bfr[4];
    #pragma unroll
    for (int mi = 0; mi < 4; ++mi)
      af[mi] = *(const bf16x8*)&As[(wm * 64 + mi * 16 + l16) * 32 + quad * 8];
    #pragma unroll
    for (int ni = 0; ni < 4; ++ni)
      bfr[ni] = *(const bf16x8*)&Bs[(wn * 64 + ni * 16 + l16) * 32 + quad * 8];
    #pragma unroll
    for (int mi = 0; mi < 4; ++mi)
      #pragma unroll
      for (int ni = 0; ni < 4; ++ni)
        acc[mi][ni] = __builtin_amdgcn_mfma_f32_16x16x32_bf16(af[mi], bfr[ni], acc[mi][ni], 0, 0, 0);
  }

  if (OUTMODE == 2) {
    // transposed bf16: rows consecutive in memory -> ushort4 per (mi,ni)
    #pragma unroll
    for (int ni = 0; ni < 4; ++ni) {
      int col = n0 + wn * 64 + ni * 16 + l16;
      #pragma unroll
      for (int mi = 0; mi < 4; ++mi) {
        int row = m0 + wm * 64 + mi * 16 + quad * 4;
        ushort4 o;
        o.x = f2bf(acc[mi][ni][0]);
        o.y = f2bf(acc[mi][ni][1]);
        o.z = f2bf(acc[mi][ni][2]);
        o.w = f2bf(acc[mi][ni][3]);
        *(ushort4*)&((u16*)Cout)[(size_t)col * M + row] = o;
      }
    }
  } else {
    #pragma unroll
    for (int ni = 0; ni < 4; ++ni) {
      int col = n0 + wn * 64 + ni * 16 + l16;
      float cs = scale_vec ? scale_vec[col] : scale_scalar;
      #pragma unroll
      for (int mi = 0; mi < 4; ++mi) {
        int row = m0 + wm * 64 + mi * 16 + quad * 4;
        #pragma unroll
        for (int r = 0; r < 4; ++r) {
          float v = acc[mi][ni][r] * cs;
          if (OUTMODE == 1)
            ((u16*)Cout)[(size_t)(row + r) * N + col] = f2bf(v);
          else
            ((float*)Cout)[(size_t)(row + r) * N + col] = v;
        }
      }
    }
  }
}

// ---------------------------------------------------------------- attention (MFMA, 1 wave per unit)
// unit = (b, n, h); CHUNK=12, PAST=12, CTX=24, P=25, D=128, SOFTCAP=50.
// q,k: [b*2400+s][1024] bf16 rows.  vt: TRANSPOSED [col][38400] bf16 (col = h*128+d), +16 u16 front slack.
// relkb: [32][1024] bf16 (rows 25..31 garbage, never used in output).
// C-layout: col = l16, row = quad*4+reg.  A-layout: A[m=l16][k=quad*8+j].
__global__ __launch_bounds__(256) void k_attn_mfma(
    const u16* __restrict__ q, const u16* __restrict__ k, const u16* __restrict__ vt,
    const u16* __restrict__ relkb, u16* __restrict__ ctx) {
  __shared__ float bdm_s[4][400];     // per-wave [16][25] row-major (flat reindex target)
  __shared__ u16 attnb[4][16 * 32];   // per-wave P matrix, A-layout staging

  const int tid = threadIdx.x;
  const int w = tid >> 6, lane = tid & 63;
  const int l16 = lane & 15, quad = lane >> 4;
  const int id = blockIdx.x * 4 + w;          // 0..25599
  const int b = id / 1600;
  const int rr = id % 1600;
  const int n = rr >> 3, h = rr & 7;
  const int s0 = n * 12;
  const size_t rowbase = (size_t)b * 2400;

  // ---- Q a-frags (m = l16 = q-row, k-chunks c: k = 32c + quad*8 + j)
  bf16x8 qf[4];
  {
    int sq = s0 + l16;
    if (sq > 2399) sq = 2399;  // pad q-rows read real data; outputs never stored
    const u16* qp = q + ((rowbase + sq) * 1024 + (size_t)h * 128 + quad * 8);
    #pragma unroll
    for (int c = 0; c < 4; ++c) qf[c] = *(const bf16x8*)(qp + 32 * c);
  }

  // ---- bd = Q @ rel_k^T  (2 p-tiles), store to LDS [16][25] for flat reindex
  #pragma unroll
  for (int pt = 0; pt < 2; ++pt) {
    int p = pt * 16 + l16;
    const u16* rp = relkb + ((size_t)p * 1024 + (size_t)h * 128 + quad * 8);
    f32x4 acc = {0.f, 0.f, 0.f, 0.f};
    #pragma unroll
    for (int c = 0; c < 4; ++c)
      acc = __builtin_amdgcn_mfma_f32_16x16x32_bf16(qf[c], *(const bf16x8*)(rp + 32 * c), acc, 0, 0, 0);
    if (p < 25) {
      #pragma unroll
      for (int r = 0; r < 4; ++r)
        bdm_s[w][(quad * 4 + r) * 25 + p] = acc[r];
    }
  }
  __threadfence_block();  // LDS write->read ordering within wave

  // ---- ac = Q @ K^T (2 t-tiles) + combine with shifted bd + softcap
  float l0[4], l1[4];
  #pragma unroll
  for (int kt = 0; kt < 2; ++kt) {
    int t = kt * 16 + l16;
    int sk = s0 - 12 + t;
    bool kvalid = ((unsigned)sk < 2400u);
    int ska = kvalid ? sk : 0;
    const u16* kp = k + ((rowbase + ska) * 1024 + (size_t)h * 128 + quad * 8);
    short km = kvalid ? (short)0xFFFF : (short)0;
    bf16x8 kmv = {km, km, km, km, km, km, km, km};
    f32x4 acc = {0.f, 0.f, 0.f, 0.f};
    #pragma unroll
    for (int c = 0; c < 4; ++c) {
      bf16x8 kf = *(const bf16x8*)(kp + 32 * c);
      kf &= kmv;  // zero-padded context rows: ac = 0, bd still enters softmax
      acc = __builtin_amdgcn_mfma_f32_16x16x32_bf16(qf[c], kf, acc, 0, 0, 0);
    }
    #pragma unroll
    for (int r = 0; r < 4; ++r) {
      float bd = bdm_s[w][(quad * 4 + r) * 24 + t];  // rel-shift = flat reindex
      float lg = tanhf((acc[r] + bd) * (1.0f / 50.0f)) * 50.0f;
      if (kt == 1 && l16 >= 8) lg = -INFINITY;  // t >= 24: outside CTX
      if (kt) l1[r] = lg; else l0[r] = lg;
    }
  }

  // ---- softmax over t (row q = quad*4+r lives in a 16-lane group)
  float at0[4], at1[4];
  #pragma unroll
  for (int r = 0; r < 4; ++r) {
    float m = fmaxf(l0[r], l1[r]);
    #pragma unroll
    for (int s = 1; s < 16; s <<= 1) m = fmaxf(m, __shfl_xor(m, s, 64));
    float e0 = __expf(l0[r] - m), e1 = __expf(l1[r] - m);
    float sum = e0 + e1;
    #pragma unroll
    for (int s = 1; s < 16; s <<= 1) sum += __shfl_xor(sum, s, 64);
    float inv = 1.0f / sum;
    at0[r] = e0 * inv;
    at1[r] = e1 * inv;
  }

  // ---- P: C-layout -> A-layout via LDS (bf16)
  #pragma unroll
  for (int r = 0; r < 4; ++r) {
    attnb[w][(quad * 4 + r) * 32 + l16] = f2bf(at0[r]);
    attnb[w][(quad * 4 + r) * 32 + 16 + l16] = f2bf(at1[r]);
  }
  __threadfence_block();
  bf16x8 af = *(const bf16x8*)&attnb[w][l16 * 32 + quad * 8];

  // ---- PV: 8 d-tiles, B-frag = V^T[d][t] contiguous in vt; mask invalid s elements
  int slo = s0 - 12 + quad * 8;
  bf16x8 vmsk;
  #pragma unroll
  for (int j = 0; j < 8; ++j)
    vmsk[j] = ((unsigned)(slo + j) < 2400u) ? (short)0xFFFF : (short)0;

  f32x4 oacc[8];
  #pragma unroll
  for (int dt = 0; dt < 8; ++dt) {
    int col = h * 128 + dt * 16 + l16;
    const u16* vp = vt + ((size_t)col * 38400 + (long)(rowbase + s0 - 12 + quad * 8));
    ushort4 va = *(const ushort4*)vp;
    ushort4 vb = *(const ushort4*)(vp + 4);
    bf16x8 vf = {(short)va.x, (short)va.y, (short)va.z, (short)va.w,
                 (short)vb.x, (short)vb.y, (short)vb.z, (short)vb.w};
    vf &= vmsk;
    f32x4 z = {0.f, 0.f, 0.f, 0.f};
    oacc[dt] = __builtin_amdgcn_mfma_f32_16x16x32_bf16(af, vf, z, 0, 0, 0);
  }

  // ---- store O (rows q = quad*4+r, only q<12 valid -> quads 0..2)
  if (quad < 3) {
    #pragma unroll
    for (int dt = 0; dt < 8; ++dt) {
      int col = h * 128 + dt * 16 + l16;
      #pragma unroll
      for (int r = 0; r < 4; ++r) {
        int qi = quad * 4 + r;
        ctx[(rowbase + s0 + qi) * 1024 + col] = f2bf(oacc[dt][r]);
      }
    }
  }
}

// ---------------------------------------------------------------- launch

extern "C" void kernel_launch(void* const* d_in, const int* in_sizes, int n_in,
                              void* d_out, int out_size, void* d_ws, size_t ws_size,
                              hipStream_t stream) {
  const float* x       = (const float*)d_in[0];  // [16,2400,1024]
  const float* pos_emb = (const float*)d_in[1];  // [25,1024]
  const float* Wq      = (const float*)d_in[2];
  const float* Wk      = (const float*)d_in[3];
  const float* Wv      = (const float*)d_in[4];
  const float* Wpost   = (const float*)d_in[5];
  const float* Wrel    = (const float*)d_in[6];
  const float* pds     = (const float*)d_in[7];  // [128]
  float* out = (float*)d_out;

  const int M = 38400, HS = 1024;           // M = B*S = 16*2400
  const size_t XE = (size_t)M * HS;

  // workspace layout (u16 units)
  u16* xbf = (u16*)d_ws;                 // XE; reused as ctx after QKV GEMMs consume it
  u16* qbf = xbf + XE;                   // XE
  u16* kbf = qbf + XE;                   // XE
  u16* vt_alloc = kbf + XE;              // XE + 64 (slack for boundary-masked loads)
  u16* vt = vt_alloc + 16;
  u16* wqt = vt_alloc + XE + 64;
  u16* wkt = wqt + (size_t)HS * HS;
  u16* wvt = wkt + (size_t)HS * HS;
  u16* wrt = wvt + (size_t)HS * HS;
  u16* wpt = wrt + (size_t)HS * HS;
  u16* relkb = wpt + (size_t)HS * HS;    // 32*1024 (rows 25..31 unwritten, harmless)
  float* qsc = (float*)(relkb + 32 * 1024);

  const double LN2 = 0.6931471805599453;
  const float QS = (float)((1.0 / sqrt(128.0)) / LN2);
  const float KS = (float)(log(1.0 + exp(1.0)) / LN2);

  // 1) x -> bf16
  k_f32_to_bf16<<<(int)(XE / 4 / 256), 256, 0, stream>>>(x, xbf, (int)(XE / 4));
  // 2) transpose weights -> bf16 [n][k]
  dim3 tg(32, 32);
  k_transpose_w<<<tg, 256, 0, stream>>>(Wq, wqt);
  k_transpose_w<<<tg, 256, 0, stream>>>(Wk, wkt);
  k_transpose_w<<<tg, 256, 0, stream>>>(Wv, wvt);
  k_transpose_w<<<tg, 256, 0, stream>>>(Wrel, wrt);
  k_transpose_w<<<tg, 256, 0, stream>>>(Wpost, wpt);
  // 3) per-column q scale
  k_qscale<<<4, 256, 0, stream>>>(pds, qsc, QS);
  // 4) rel_k = pos_emb @ Wrel -> bf16
  k_relk<<<dim3(4, 25), 256, 0, stream>>>(pos_emb, wrt, relkb);
  // 5) QKV projections
  dim3 gg(HS / 128, M / 128);  // (8, 300)
  k_gemm_bt<1><<<gg, 256, 0, stream>>>(xbf, wqt, qbf, qsc, 1.0f, M, HS, HS);
  k_gemm_bt<1><<<gg, 256, 0, stream>>>(xbf, wkt, kbf, nullptr, KS, M, HS, HS);
  k_gemm_bt<2><<<gg, 256, 0, stream>>>(xbf, wvt, vt, nullptr, 1.0f, M, HS, HS);  // V transposed
  // 6) attention -> ctx (reuses xbf region; stream-ordered after QKV reads)
  k_attn_mfma<<<25600 / 4, 256, 0, stream>>>(qbf, kbf, vt, relkb, xbf);
  // 7) out = ctx @ Wpost (fp32 out)
  k_gemm_bt<0><<<gg, 256, 0, stream>>>(xbf, wpt, out, nullptr, 1.0f, M, HS, HS);
}